// Round 8
// baseline (289.675 us; speedup 1.0000x reference)
//
#include <hip/hip_runtime.h>
#include <hip/hip_bf16.h>

// SAGE 2-layer forward, R13:
//   neigh1 = segment_mean(x[src]); h = relu(x@Ws1 + neigh1@Wn1 + b1)   [bf16 MFMA]
//   z = h@Wn2, s = h@Ws2; out = log_softmax(s + segment_mean(z) + b2)
// R13 = R12 (242.9, best) + degree precompute:
//   - pass A emits fire-and-forget atomicAdd(&deg[dst],1) (global, no-return ->
//     no waitcnt; hides under the LDS-atomic-bound multisplit loop).
//   - build_csr2 drops its histogram pass (was: full 6.4MB cbuf stream + 1.6M
//     LDS atomics, only to get per-node degrees): loads deg[] coalesced, scans,
//     scatters. Keeps only the irreducible scatter pass.
//   - deg memset folded into the ccursor memset (adjacent alloc, one call).
// Structure lessons: R8 (fuse agg into gemm: -occupancy, 303), R9 (y-GEMM in prep
// shadow: saturated, 254), R10 (BATCH 8192: VGPR pressure, 250), R11 (sort+agg
// coupling: 256). Split stages + fine grids win.

#define N_FEAT 128
#define CSHIFT 9                  // 512 nodes per coarse bucket
#define CNODES 512
#define NBINS 256                 // scan width in pass A (bins 196..255 empty)
#define CCAP 9728                 // mean 8192, sd ~90 -> +17 sigma
#define BATCH 4096                // edges per pass-A block
#define EPT 16                    // edges per thread in pass A
#define BF_BLOCKS 256
#define PW_BLOCKS 128

typedef __attribute__((ext_vector_type(8))) short short8;
typedef __attribute__((ext_vector_type(8))) unsigned short ushort8_t;
typedef __attribute__((ext_vector_type(16))) float f32x16;

__device__ __forceinline__ float bf16_bits_to_f32(ushort u) {
    union { unsigned int i; float f; } c;
    c.i = ((unsigned int)u) << 16;
    return c.f;
}
__device__ __forceinline__ ushort f32_to_bf16_bits(float f) {
    return __bfloat16_as_ushort(__float2bfloat16(f));
}

// Fused: pass-A multisplit | x->bf16 conversion | weight prep. Independent block ranges.
// pack = (d&511)<<17 | src.
__global__ __launch_bounds__(256) void prep_and_split_kernel(
    const int* __restrict__ src, const int* __restrict__ dst,
    int* __restrict__ ccursor, int* __restrict__ deg,
    unsigned* __restrict__ cbuf, int E,
    const float* __restrict__ x, ushort* __restrict__ xb, int n4,
    const float* __restrict__ w1, const float* __restrict__ w2,
    ushort* __restrict__ wt, int nms) {
    __shared__ unsigned stage[BATCH];
    __shared__ int cntw[4][NBINS];     // reused as stage_b[BATCH] bytes after scan
    __shared__ int curw[4][NBINS];
    __shared__ int excl[NBINS];
    __shared__ int gpos[NBINS];
    __shared__ int wsum[4];
    int tid = threadIdx.x;
    int bid = blockIdx.x;

    if (bid >= nms) {
        int rb = bid - nms;
        if (rb < BF_BLOCKS) {
            // to_bf16: grid-stride over float4 chunks
            int i = rb * 256 + tid;
            int stride = BF_BLOCKS * 256;
            for (; i < n4; i += stride) {
                float4 v = ((const float4*)x)[i];
                ushort4 r;
                r.x = f32_to_bf16_bits(v.x);
                r.y = f32_to_bf16_bits(v.y);
                r.z = f32_to_bf16_bits(v.z);
                r.w = f32_to_bf16_bits(v.w);
                ((ushort4*)xb)[i] = r;
            }
        } else {
            // prep_weights: Wt[n=128][k=256] bf16 from w1 (k 0..127) / w2 (k 128..255)
            int id = (rb - BF_BLOCKS) * 256 + tid;   // exactly 128*256 ids
            int nn = id >> 8;
            int k = id & 255;
            float v = (k < 128) ? w1[k * 128 + nn] : w2[(k - 128) * 128 + nn];
            wt[nn * 256 + k] = f32_to_bf16_bits(v);
        }
        return;
    }

    // ---- multisplit branch ----
    int wv = tid >> 6;
    int lane = tid & 63;
    int base = bid * BATCH;
    int total = min(BATCH, E - base);

    unsigned pk[EPT];
    int bn[EPT];
    for (int i = tid; i < 4 * NBINS; i += 256) ((int*)cntw)[i] = 0;
    __syncthreads();
    #pragma unroll
    for (int k = 0; k < EPT; ++k) {
        int e = base + k * 256 + tid;
        if (e < E) {
            int d = dst[e];
            int sv = src[e];
            bn[k] = d >> CSHIFT;
            pk[k] = ((unsigned)(d & (CNODES - 1)) << 17) | (unsigned)sv;
            atomicAdd(&cntw[wv][bn[k]], 1);
            atomicAdd(&deg[d], 1);   // fire-and-forget; consumed by build_csr2
        } else {
            bn[k] = -1;
        }
    }
    __syncthreads();
    // per-bin totals + per-wave exclusive prefixes (column tid only -> no hazard)
    int c0 = cntw[0][tid], c1 = cntw[1][tid], c2 = cntw[2][tid], c3 = cntw[3][tid];
    int c = c0 + c1 + c2 + c3;
    // inclusive scan of c over 256 threads: wave shfl scan + cross-wave offset
    int val = c;
    #pragma unroll
    for (int off = 1; off < 64; off <<= 1) {
        int t = __shfl_up(val, off);
        if (lane >= off) val += t;
    }
    if (lane == 63) wsum[wv] = val;
    __syncthreads();
    #pragma unroll
    for (int i = 0; i < 4; ++i)
        if (i < wv) val += wsum[i];
    int e0 = val - c;
    excl[tid] = e0;
    curw[0][tid] = e0;
    curw[1][tid] = e0 + c0;
    curw[2][tid] = e0 + c0 + c1;
    curw[3][tid] = e0 + c0 + c1 + c2;
    gpos[tid] = (c > 0) ? atomicAdd(&ccursor[tid], c) : 0;
    __syncthreads();   // cntw dead from here: its 4KB is reused as stage_b bytes
    unsigned char* stage_b = (unsigned char*)cntw;
    // shuffle into staging (bucket-sorted within block); per-wave counters cut contention 4x
    #pragma unroll
    for (int k = 0; k < EPT; ++k) {
        if (bn[k] >= 0) {
            int ofs = atomicAdd(&curw[wv][bn[k]], 1);
            stage[ofs] = pk[k];
            stage_b[ofs] = (unsigned char)bn[k];
        }
    }
    __syncthreads();
    // flush: consecutive i within a bucket -> consecutive global targets
    for (int i = tid; i < total; i += 256) {
        int b = stage_b[i];
        int target = gpos[b] + (i - excl[b]);
        cbuf[(size_t)b * CCAP + target] = stage[i];
    }
}

// Pass B: one block (512 thr) per coarse bucket. Degrees precomputed by pass A ->
// no histogram pass: coalesced deg load, scan, scatter into CSR window.
__global__ __launch_bounds__(512) void build_csr2_kernel(
    const unsigned* __restrict__ cbuf, const int* __restrict__ ccnt,
    const int* __restrict__ deg, int* __restrict__ row_ptr,
    int* __restrict__ csr, int N, int E) {
    __shared__ int cur[CNODES];
    __shared__ int wred[8];
    __shared__ int cstart_s;
    int cb = blockIdx.x;
    int tid = threadIdx.x;
    int lane = tid & 63;
    int w = tid >> 6;
    int node = cb * CNODES + tid;

    // cstart = sum of ccnt[0..cb-1] via block reduce (cb <= 195 < 512)
    int v = (tid < cb) ? ccnt[tid] : 0;
    #pragma unroll
    for (int off = 32; off > 0; off >>= 1) v += __shfl_xor(v, off);
    if (lane == 0) wred[w] = v;
    __syncthreads();
    if (tid == 0) {
        int t = 0;
        #pragma unroll
        for (int i = 0; i < 8; ++i) t += wred[i];
        cstart_s = t;
    }
    if (cb == 0 && tid == 0) row_ptr[N] = E;
    int cnt = ccnt[cb];
    size_t bbase = (size_t)cb * CCAP;
    __syncthreads();
    int base = cstart_s;

    int c = (node < N) ? deg[node] : 0;
    // inclusive scan over 512 threads: wave shfl scan + cross-wave offsets
    int val = c;
    #pragma unroll
    for (int off = 1; off < 64; off <<= 1) {
        int t = __shfl_up(val, off);
        if (lane >= off) val += t;
    }
    if (lane == 63) wred[w] = val;
    __syncthreads();
    #pragma unroll
    for (int i = 0; i < 8; ++i)
        if (i < w) val += wred[i];
    int excl = val - c;
    if (node < N) row_ptr[node] = base + excl;
    cur[tid] = excl;
    __syncthreads();
    for (int e = tid; e < cnt; e += 512) {
        unsigned p = cbuf[bbase + e];
        int bin = p >> 17;
        int ofs = atomicAdd(&cur[bin], 1);
        csr[base + ofs] = (int)(p & 0x1FFFF);
    }
}

// One wave per node; 16B/lane gathers: lane = (sub:2, fc:4); lane group sub handles
// edge e+sub, feature chunk fc*8..fc*8+7. 4 rows (1KB) per wave-load instruction.
__global__ __launch_bounds__(256) void aggregate_bf16_kernel(
    const ushort* __restrict__ xb, const int* __restrict__ row_ptr,
    const int* __restrict__ csr, ushort* __restrict__ out, int n) {
    int v = blockIdx.x * 4 + (threadIdx.x >> 6);
    int lane = threadIdx.x & 63;
    int sub = lane >> 4;
    int fc = lane & 15;
    if (v >= n) return;
    int beg = row_ptr[v];
    int end = row_ptr[v + 1];
    float acc[8];
    #pragma unroll
    for (int j = 0; j < 8; ++j) acc[j] = 0.f;
    const ushort* xfc = xb + fc * 8;
    int e = beg;
    for (; e + 16 <= end; e += 16) {
        int s0 = csr[e + sub];
        int s1 = csr[e + 4 + sub];
        int s2 = csr[e + 8 + sub];
        int s3 = csr[e + 12 + sub];
        ushort8_t t0 = *(const ushort8_t*)(xfc + (size_t)s0 * N_FEAT);
        ushort8_t t1 = *(const ushort8_t*)(xfc + (size_t)s1 * N_FEAT);
        ushort8_t t2 = *(const ushort8_t*)(xfc + (size_t)s2 * N_FEAT);
        ushort8_t t3 = *(const ushort8_t*)(xfc + (size_t)s3 * N_FEAT);
        #pragma unroll
        for (int j = 0; j < 8; ++j) acc[j] += bf16_bits_to_f32(t0[j]);
        #pragma unroll
        for (int j = 0; j < 8; ++j) acc[j] += bf16_bits_to_f32(t1[j]);
        #pragma unroll
        for (int j = 0; j < 8; ++j) acc[j] += bf16_bits_to_f32(t2[j]);
        #pragma unroll
        for (int j = 0; j < 8; ++j) acc[j] += bf16_bits_to_f32(t3[j]);
    }
    if (e + 8 <= end) {
        int s0 = csr[e + sub];
        int s1 = csr[e + 4 + sub];
        ushort8_t t0 = *(const ushort8_t*)(xfc + (size_t)s0 * N_FEAT);
        ushort8_t t1 = *(const ushort8_t*)(xfc + (size_t)s1 * N_FEAT);
        #pragma unroll
        for (int j = 0; j < 8; ++j) acc[j] += bf16_bits_to_f32(t0[j]);
        #pragma unroll
        for (int j = 0; j < 8; ++j) acc[j] += bf16_bits_to_f32(t1[j]);
        e += 8;
    }
    if (e + 4 <= end) {
        int s0 = csr[e + sub];
        ushort8_t t0 = *(const ushort8_t*)(xfc + (size_t)s0 * N_FEAT);
        #pragma unroll
        for (int j = 0; j < 8; ++j) acc[j] += bf16_bits_to_f32(t0[j]);
        e += 4;
    }
    int rem = end - e;
    if (sub < rem) {
        int s0 = csr[e + sub];
        ushort8_t t0 = *(const ushort8_t*)(xfc + (size_t)s0 * N_FEAT);
        #pragma unroll
        for (int j = 0; j < 8; ++j) acc[j] += bf16_bits_to_f32(t0[j]);
    }
    // reduce across the 4 sub groups (lanes l, l^16, l^32, l^48)
    #pragma unroll
    for (int j = 0; j < 8; ++j) {
        acc[j] += __shfl_xor(acc[j], 16);
        acc[j] += __shfl_xor(acc[j], 32);
    }
    if (lane < 16) {
        int deg = end - beg;
        float inv = (deg > 0) ? 1.0f / (float)deg : 0.0f;
        ushort8_t r;
        #pragma unroll
        for (int j = 0; j < 8; ++j)
            r[j] = f32_to_bf16_bits(acc[j] * inv);
        *(ushort8_t*)(out + (size_t)v * N_FEAT + lane * 8) = r;
    }
}

// gemm1 + layer2a fused: per 128-node block compute h = relu([x|neigh]@Wt^T + b1)
// in fp32 accumulators, then s = h@Ws2, z = h@Wn2 via 32-lane shuffle reduction.
// h is never materialized.
__global__ __launch_bounds__(256) void gemm1_fused_kernel(
    const ushort* __restrict__ xb, const ushort* __restrict__ nbb,
    const ushort* __restrict__ wt, const float* __restrict__ b,
    const float* __restrict__ ws2, const float* __restrict__ wn2,
    float* __restrict__ s_out, float* __restrict__ z_out, int n) {
    __shared__ ushort As[128 * 72];
    __shared__ ushort Bs[128 * 72];
    int tid = threadIdx.x;
    int wave = tid >> 6;
    int lane = tid & 63;
    int m = lane & 31;
    int half = lane >> 5;
    int block_row = blockIdx.x * 128;

    f32x16 acc[4];
    #pragma unroll
    for (int t = 0; t < 4; ++t)
        #pragma unroll
        for (int i = 0; i < 16; ++i) acc[t][i] = 0.0f;

    for (int kc = 0; kc < 4; ++kc) {
        const ushort* A = (kc < 2) ? xb : nbb;
        int k0 = (kc & 1) * 64;
        #pragma unroll
        for (int l = 0; l < 4; ++l) {
            int idx = l * 256 + tid;
            int r = idx >> 3;
            int p = idx & 7;
            int node = block_row + r;
            ushort8_t v;
            if (node < n) {
                v = *(const ushort8_t*)(A + (size_t)node * N_FEAT + k0 + p * 8);
            } else {
                #pragma unroll
                for (int q = 0; q < 8; ++q) v[q] = 0;
            }
            *(ushort8_t*)(&As[r * 72 + p * 8]) = v;
        }
        #pragma unroll
        for (int l = 0; l < 4; ++l) {
            int idx = l * 256 + tid;
            int cc = idx >> 3;
            int p = idx & 7;
            ushort8_t v = *(const ushort8_t*)(wt + (size_t)cc * 256 + kc * 64 + p * 8);
            *(ushort8_t*)(&Bs[cc * 72 + p * 8]) = v;
        }
        __syncthreads();
        #pragma unroll
        for (int ks = 0; ks < 4; ++ks) {
            int koff = ks * 16 + half * 8;
            short8 a = *(const short8*)(&As[(32 * wave + m) * 72 + koff]);
            short8 bf0 = *(const short8*)(&Bs[(0 * 32 + m) * 72 + koff]);
            short8 bf1 = *(const short8*)(&Bs[(1 * 32 + m) * 72 + koff]);
            short8 bf2 = *(const short8*)(&Bs[(2 * 32 + m) * 72 + koff]);
            short8 bf3 = *(const short8*)(&Bs[(3 * 32 + m) * 72 + koff]);
            acc[0] = __builtin_amdgcn_mfma_f32_32x32x16_bf16(a, bf0, acc[0], 0, 0, 0);
            acc[1] = __builtin_amdgcn_mfma_f32_32x32x16_bf16(a, bf1, acc[1], 0, 0, 0);
            acc[2] = __builtin_amdgcn_mfma_f32_32x32x16_bf16(a, bf2, acc[2], 0, 0, 0);
            acc[3] = __builtin_amdgcn_mfma_f32_32x32x16_bf16(a, bf3, acc[3], 0, 0, 0);
        }
        __syncthreads();
    }

    // epilogue: per lane, cols {m, 32+m, 64+m, 96+m}; rows (reg,half).
    float bcol[4], wsc[4][2], wnc[4][2];
    #pragma unroll
    for (int t = 0; t < 4; ++t) {
        int col = t * 32 + m;
        bcol[t] = b[col];
        float2 a = ((const float2*)ws2)[col];   // w_self2[col][0..1]
        float2 q = ((const float2*)wn2)[col];   // w_neigh2[col][0..1]
        wsc[t][0] = a.x; wsc[t][1] = a.y;
        wnc[t][0] = q.x; wnc[t][1] = q.y;
    }
    #pragma unroll
    for (int reg = 0; reg < 16; ++reg) {
        int rowin = (reg & 3) + 8 * (reg >> 2) + 4 * half;
        int node = block_row + 32 * wave + rowin;
        float p0 = 0.f, p1 = 0.f, q0 = 0.f, q1 = 0.f;
        #pragma unroll
        for (int t = 0; t < 4; ++t) {
            float hv = fmaxf(acc[t][reg] + bcol[t], 0.0f);
            p0 += hv * wsc[t][0]; p1 += hv * wsc[t][1];
            q0 += hv * wnc[t][0]; q1 += hv * wnc[t][1];
        }
        // reduce over the 32 lanes of this half (cols are disjoint across m)
        #pragma unroll
        for (int off = 1; off < 32; off <<= 1) {
            p0 += __shfl_xor(p0, off);
            p1 += __shfl_xor(p1, off);
            q0 += __shfl_xor(q0, off);
            q1 += __shfl_xor(q1, off);
        }
        if (m == 0 && node < n) {
            ((float2*)s_out)[node] = make_float2(p0, p1);
            ((float2*)z_out)[node] = make_float2(q0, q1);
        }
    }
}

// Layer-2 part B: 16 lanes per node; lane-per-edge z gather (L2-resident),
// shfl-xor group reduce, add self + bias, log_softmax.
__global__ __launch_bounds__(256) void layer2b_kernel(
    const float* __restrict__ s_in, const float* __restrict__ z,
    const int* __restrict__ row_ptr, const int* __restrict__ csr,
    const float* __restrict__ b, float* __restrict__ out, int n) {
    int v = blockIdx.x * 16 + (threadIdx.x >> 4);
    int sl = threadIdx.x & 15;
    if (v >= n) return;
    int beg = row_ptr[v];
    int end = row_ptr[v + 1];
    float a0 = 0.f, a1 = 0.f;
    for (int e = beg + sl; e < end; e += 16) {
        float2 t = ((const float2*)z)[csr[e]];
        a0 += t.x; a1 += t.y;
    }
    // reduce within the 16-lane group (xor offsets stay inside the group)
    #pragma unroll
    for (int off = 8; off > 0; off >>= 1) {
        a0 += __shfl_xor(a0, off);
        a1 += __shfl_xor(a1, off);
    }
    if (sl == 0) {
        int deg = end - beg;
        float inv = (deg > 0) ? 1.0f / (float)deg : 0.0f;
        float2 sv = ((const float2*)s_in)[v];
        float o0 = sv.x + a0 * inv + b[0];
        float o1 = sv.y + a1 * inv + b[1];
        float mx = fmaxf(o0, o1);
        float lse = mx + logf(expf(o0 - mx) + expf(o1 - mx));
        ((float2*)out)[v] = make_float2(o0 - lse, o1 - lse);
    }
}

extern "C" void kernel_launch(void* const* d_in, const int* in_sizes, int n_in,
                              void* d_out, int out_size, void* d_ws, size_t ws_size,
                              hipStream_t stream) {
    const float* x        = (const float*)d_in[0];
    const int*   src      = (const int*)d_in[1];
    const int*   dst      = (const int*)d_in[2];
    const float* w_self1  = (const float*)d_in[3];
    const float* w_neigh1 = (const float*)d_in[4];
    const float* b1       = (const float*)d_in[5];
    const float* w_self2  = (const float*)d_in[6];
    const float* w_neigh2 = (const float*)d_in[7];
    const float* b2       = (const float*)d_in[8];
    float* out = (float*)d_out;

    int N = in_sizes[0] / N_FEAT;
    int E = in_sizes[1];
    int nbk = (N + CNODES - 1) / CNODES;  // 196 for N=100000
    int nms = (E + BATCH - 1) / BATCH;    // 391 for E=1.6M

    char* ws = (char*)d_ws;
    size_t off = 0;
    auto alloc = [&](size_t bytes) -> void* {
        void* p = ws + off;
        off += (bytes + 255) & ~(size_t)255;
        return p;
    };
    int*      ccursor = (int*)alloc(NBINS * 4);
    int*      deg     = (int*)alloc((size_t)N * 4);      // adjacent to ccursor: one memset
    int*      row_ptr = (int*)alloc((size_t)(N + 1) * 4);
    int*      csr     = (int*)alloc((size_t)E * 4);
    unsigned* cbuf    = (unsigned*)alloc((size_t)nbk * CCAP * 4);
    ushort*   xb      = (ushort*)alloc((size_t)N * N_FEAT * 2);
    ushort*   nbb     = (ushort*)alloc((size_t)N * N_FEAT * 2);
    ushort*   wt      = (ushort*)alloc((size_t)128 * 256 * 2);
    float*    s_buf   = (float*)alloc((size_t)N * 2 * 4);
    float*    z_buf   = (float*)alloc((size_t)N * 2 * 4);
    (void)ws_size; (void)n_in; (void)out_size;

    size_t zero_bytes = (size_t)((char*)row_ptr - (char*)ccursor);
    hipMemsetAsync(ccursor, 0, zero_bytes, stream);

    prep_and_split_kernel<<<nms + BF_BLOCKS + PW_BLOCKS, 256, 0, stream>>>(
        src, dst, ccursor, deg, cbuf, E, x, xb, N * N_FEAT / 4, w_self1, w_neigh1, wt, nms);
    build_csr2_kernel<<<nbk, 512, 0, stream>>>(cbuf, ccursor, deg, row_ptr, csr, N, E);
    aggregate_bf16_kernel<<<(N + 3) / 4, 256, 0, stream>>>(xb, row_ptr, csr, nbb, N);
    gemm1_fused_kernel<<<(N + 127) / 128, 256, 0, stream>>>(
        xb, nbb, wt, b1, w_self2, w_neigh2, s_buf, z_buf, N);
    layer2b_kernel<<<(N + 15) / 16, 256, 0, stream>>>(s_buf, z_buf, row_ptr, csr, b2, out, N);
}

// Round 9
// 242.027 us; speedup vs baseline: 1.1969x; 1.1969x over previous
//
#include <hip/hip_runtime.h>
#include <hip/hip_bf16.h>

// SAGE 2-layer forward, R14 == R12 (measured best, 242.9 us).
//   neigh1 = segment_mean(x[src]); h = relu(x@Ws1 + neigh1@Wn1 + b1)   [bf16 MFMA]
//   z = h@Wn2, s = h@Ws2; out = log_softmax(s + segment_mean(z) + b2)
// R13 (deg precompute via global atomicAdd in pass A) regressed 242.9->289.7:
//   1.6M random global atomics serialized in L2 atomic units -> prep 88-92us,
//   VALUBusy 2%. Scattered global atomics at edge rate are ~10x the LDS
//   histogram they replaced. REVERTED.
// Structure lessons (7 decompositions tested): R8 fuse-agg-into-gemm 303 (LDS
// kills occupancy; gather needs ~22 waves/CU); R9 y-GEMM-in-prep-shadow 254
// (shadow saturated); R10 BATCH-8192 250 (VGPR pressure); R11 sort+agg merge
// 256 (bucket-grain blocks starve gather); R13 deg-atomics 290. Split stages,
// fine grids, LDS histograms win. Aggregate pinned at 57us (beyond-L2 random
// gather service rate, invariant across all rounds).

#define N_FEAT 128
#define CSHIFT 9                  // 512 nodes per coarse bucket
#define CNODES 512
#define NBINS 256                 // scan width in pass A (bins 196..255 empty)
#define CCAP 9728                 // mean 8192, sd ~90 -> +17 sigma
#define BATCH 4096                // edges per pass-A block
#define EPT 16                    // edges per thread in pass A
#define BF_BLOCKS 256
#define PW_BLOCKS 128

typedef __attribute__((ext_vector_type(8))) short short8;
typedef __attribute__((ext_vector_type(8))) unsigned short ushort8_t;
typedef __attribute__((ext_vector_type(16))) float f32x16;

__device__ __forceinline__ float bf16_bits_to_f32(ushort u) {
    union { unsigned int i; float f; } c;
    c.i = ((unsigned int)u) << 16;
    return c.f;
}
__device__ __forceinline__ ushort f32_to_bf16_bits(float f) {
    return __bfloat16_as_ushort(__float2bfloat16(f));
}

// Fused: pass-A multisplit | x->bf16 conversion | weight prep. Independent block ranges.
// pack = (d&511)<<17 | src.
__global__ __launch_bounds__(256) void prep_and_split_kernel(
    const int* __restrict__ src, const int* __restrict__ dst,
    int* __restrict__ ccursor, unsigned* __restrict__ cbuf, int E,
    const float* __restrict__ x, ushort* __restrict__ xb, int n4,
    const float* __restrict__ w1, const float* __restrict__ w2,
    ushort* __restrict__ wt, int nms) {
    __shared__ unsigned stage[BATCH];
    __shared__ int cntw[4][NBINS];     // reused as stage_b[BATCH] bytes after scan
    __shared__ int curw[4][NBINS];
    __shared__ int excl[NBINS];
    __shared__ int gpos[NBINS];
    __shared__ int wsum[4];
    int tid = threadIdx.x;
    int bid = blockIdx.x;

    if (bid >= nms) {
        int rb = bid - nms;
        if (rb < BF_BLOCKS) {
            // to_bf16: grid-stride over float4 chunks
            int i = rb * 256 + tid;
            int stride = BF_BLOCKS * 256;
            for (; i < n4; i += stride) {
                float4 v = ((const float4*)x)[i];
                ushort4 r;
                r.x = f32_to_bf16_bits(v.x);
                r.y = f32_to_bf16_bits(v.y);
                r.z = f32_to_bf16_bits(v.z);
                r.w = f32_to_bf16_bits(v.w);
                ((ushort4*)xb)[i] = r;
            }
        } else {
            // prep_weights: Wt[n=128][k=256] bf16 from w1 (k 0..127) / w2 (k 128..255)
            int id = (rb - BF_BLOCKS) * 256 + tid;   // exactly 128*256 ids
            int nn = id >> 8;
            int k = id & 255;
            float v = (k < 128) ? w1[k * 128 + nn] : w2[(k - 128) * 128 + nn];
            wt[nn * 256 + k] = f32_to_bf16_bits(v);
        }
        return;
    }

    // ---- multisplit branch ----
    int wv = tid >> 6;
    int lane = tid & 63;
    int base = bid * BATCH;
    int total = min(BATCH, E - base);

    unsigned pk[EPT];
    int bn[EPT];
    for (int i = tid; i < 4 * NBINS; i += 256) ((int*)cntw)[i] = 0;
    __syncthreads();
    #pragma unroll
    for (int k = 0; k < EPT; ++k) {
        int e = base + k * 256 + tid;
        if (e < E) {
            int d = dst[e];
            int sv = src[e];
            bn[k] = d >> CSHIFT;
            pk[k] = ((unsigned)(d & (CNODES - 1)) << 17) | (unsigned)sv;
            atomicAdd(&cntw[wv][bn[k]], 1);
        } else {
            bn[k] = -1;
        }
    }
    __syncthreads();
    // per-bin totals + per-wave exclusive prefixes (column tid only -> no hazard)
    int c0 = cntw[0][tid], c1 = cntw[1][tid], c2 = cntw[2][tid], c3 = cntw[3][tid];
    int c = c0 + c1 + c2 + c3;
    // inclusive scan of c over 256 threads: wave shfl scan + cross-wave offset
    int val = c;
    #pragma unroll
    for (int off = 1; off < 64; off <<= 1) {
        int t = __shfl_up(val, off);
        if (lane >= off) val += t;
    }
    if (lane == 63) wsum[wv] = val;
    __syncthreads();
    #pragma unroll
    for (int i = 0; i < 4; ++i)
        if (i < wv) val += wsum[i];
    int e0 = val - c;
    excl[tid] = e0;
    curw[0][tid] = e0;
    curw[1][tid] = e0 + c0;
    curw[2][tid] = e0 + c0 + c1;
    curw[3][tid] = e0 + c0 + c1 + c2;
    gpos[tid] = (c > 0) ? atomicAdd(&ccursor[tid], c) : 0;
    __syncthreads();   // cntw dead from here: its 4KB is reused as stage_b bytes
    unsigned char* stage_b = (unsigned char*)cntw;
    // shuffle into staging (bucket-sorted within block); per-wave counters cut contention 4x
    #pragma unroll
    for (int k = 0; k < EPT; ++k) {
        if (bn[k] >= 0) {
            int ofs = atomicAdd(&curw[wv][bn[k]], 1);
            stage[ofs] = pk[k];
            stage_b[ofs] = (unsigned char)bn[k];
        }
    }
    __syncthreads();
    // flush: consecutive i within a bucket -> consecutive global targets
    for (int i = tid; i < total; i += 256) {
        int b = stage_b[i];
        int target = gpos[b] + (i - excl[b]);
        cbuf[(size_t)b * CCAP + target] = stage[i];
    }
}

// Pass B: one block (512 thr) per coarse bucket. Inline coarse prefix (block reduce),
// counting sort into the bucket's contiguous CSR window.
__global__ __launch_bounds__(512) void build_csr2_kernel(
    const unsigned* __restrict__ cbuf, const int* __restrict__ ccnt,
    int* __restrict__ row_ptr, int* __restrict__ csr, int N, int E) {
    __shared__ int hist[CNODES];
    __shared__ int cur[CNODES];
    __shared__ int wred[8];
    __shared__ int cstart_s;
    int cb = blockIdx.x;
    int tid = threadIdx.x;
    int lane = tid & 63;
    int w = tid >> 6;

    // cstart = sum of ccnt[0..cb-1] via block reduce (cb <= 195 < 512)
    int v = (tid < cb) ? ccnt[tid] : 0;
    #pragma unroll
    for (int off = 32; off > 0; off >>= 1) v += __shfl_xor(v, off);
    if (lane == 0) wred[w] = v;
    hist[tid] = 0;
    __syncthreads();
    if (tid == 0) {
        int t = 0;
        #pragma unroll
        for (int i = 0; i < 8; ++i) t += wred[i];
        cstart_s = t;
    }
    if (cb == 0 && tid == 0) row_ptr[N] = E;
    int cnt = ccnt[cb];
    size_t bbase = (size_t)cb * CCAP;
    __syncthreads();
    int base = cstart_s;

    for (int e = tid; e < cnt; e += 512) {
        unsigned p = cbuf[bbase + e];
        atomicAdd(&hist[p >> 17], 1);
    }
    __syncthreads();
    int c = hist[tid];
    // inclusive scan over 512 threads: wave shfl scan + cross-wave offsets
    int val = c;
    #pragma unroll
    for (int off = 1; off < 64; off <<= 1) {
        int t = __shfl_up(val, off);
        if (lane >= off) val += t;
    }
    if (lane == 63) wred[w] = val;
    __syncthreads();
    #pragma unroll
    for (int i = 0; i < 8; ++i)
        if (i < w) val += wred[i];
    int excl = val - c;
    int node = cb * CNODES + tid;
    if (node < N) row_ptr[node] = base + excl;
    cur[tid] = excl;
    __syncthreads();
    for (int e = tid; e < cnt; e += 512) {
        unsigned p = cbuf[bbase + e];
        int bin = p >> 17;
        int ofs = atomicAdd(&cur[bin], 1);
        csr[base + ofs] = (int)(p & 0x1FFFF);
    }
}

// One wave per node; 16B/lane gathers: lane = (sub:2, fc:4); lane group sub handles
// edge e+sub, feature chunk fc*8..fc*8+7. 4 rows (1KB) per wave-load instruction.
__global__ __launch_bounds__(256) void aggregate_bf16_kernel(
    const ushort* __restrict__ xb, const int* __restrict__ row_ptr,
    const int* __restrict__ csr, ushort* __restrict__ out, int n) {
    int v = blockIdx.x * 4 + (threadIdx.x >> 6);
    int lane = threadIdx.x & 63;
    int sub = lane >> 4;
    int fc = lane & 15;
    if (v >= n) return;
    int beg = row_ptr[v];
    int end = row_ptr[v + 1];
    float acc[8];
    #pragma unroll
    for (int j = 0; j < 8; ++j) acc[j] = 0.f;
    const ushort* xfc = xb + fc * 8;
    int e = beg;
    for (; e + 16 <= end; e += 16) {
        int s0 = csr[e + sub];
        int s1 = csr[e + 4 + sub];
        int s2 = csr[e + 8 + sub];
        int s3 = csr[e + 12 + sub];
        ushort8_t t0 = *(const ushort8_t*)(xfc + (size_t)s0 * N_FEAT);
        ushort8_t t1 = *(const ushort8_t*)(xfc + (size_t)s1 * N_FEAT);
        ushort8_t t2 = *(const ushort8_t*)(xfc + (size_t)s2 * N_FEAT);
        ushort8_t t3 = *(const ushort8_t*)(xfc + (size_t)s3 * N_FEAT);
        #pragma unroll
        for (int j = 0; j < 8; ++j) acc[j] += bf16_bits_to_f32(t0[j]);
        #pragma unroll
        for (int j = 0; j < 8; ++j) acc[j] += bf16_bits_to_f32(t1[j]);
        #pragma unroll
        for (int j = 0; j < 8; ++j) acc[j] += bf16_bits_to_f32(t2[j]);
        #pragma unroll
        for (int j = 0; j < 8; ++j) acc[j] += bf16_bits_to_f32(t3[j]);
    }
    if (e + 8 <= end) {
        int s0 = csr[e + sub];
        int s1 = csr[e + 4 + sub];
        ushort8_t t0 = *(const ushort8_t*)(xfc + (size_t)s0 * N_FEAT);
        ushort8_t t1 = *(const ushort8_t*)(xfc + (size_t)s1 * N_FEAT);
        #pragma unroll
        for (int j = 0; j < 8; ++j) acc[j] += bf16_bits_to_f32(t0[j]);
        #pragma unroll
        for (int j = 0; j < 8; ++j) acc[j] += bf16_bits_to_f32(t1[j]);
        e += 8;
    }
    if (e + 4 <= end) {
        int s0 = csr[e + sub];
        ushort8_t t0 = *(const ushort8_t*)(xfc + (size_t)s0 * N_FEAT);
        #pragma unroll
        for (int j = 0; j < 8; ++j) acc[j] += bf16_bits_to_f32(t0[j]);
        e += 4;
    }
    int rem = end - e;
    if (sub < rem) {
        int s0 = csr[e + sub];
        ushort8_t t0 = *(const ushort8_t*)(xfc + (size_t)s0 * N_FEAT);
        #pragma unroll
        for (int j = 0; j < 8; ++j) acc[j] += bf16_bits_to_f32(t0[j]);
    }
    // reduce across the 4 sub groups (lanes l, l^16, l^32, l^48)
    #pragma unroll
    for (int j = 0; j < 8; ++j) {
        acc[j] += __shfl_xor(acc[j], 16);
        acc[j] += __shfl_xor(acc[j], 32);
    }
    if (lane < 16) {
        int deg = end - beg;
        float inv = (deg > 0) ? 1.0f / (float)deg : 0.0f;
        ushort8_t r;
        #pragma unroll
        for (int j = 0; j < 8; ++j)
            r[j] = f32_to_bf16_bits(acc[j] * inv);
        *(ushort8_t*)(out + (size_t)v * N_FEAT + lane * 8) = r;
    }
}

// gemm1 + layer2a fused: per 128-node block compute h = relu([x|neigh]@Wt^T + b1)
// in fp32 accumulators, then s = h@Ws2, z = h@Wn2 via 32-lane shuffle reduction.
// h is never materialized.
__global__ __launch_bounds__(256) void gemm1_fused_kernel(
    const ushort* __restrict__ xb, const ushort* __restrict__ nbb,
    const ushort* __restrict__ wt, const float* __restrict__ b,
    const float* __restrict__ ws2, const float* __restrict__ wn2,
    float* __restrict__ s_out, float* __restrict__ z_out, int n) {
    __shared__ ushort As[128 * 72];
    __shared__ ushort Bs[128 * 72];
    int tid = threadIdx.x;
    int wave = tid >> 6;
    int lane = tid & 63;
    int m = lane & 31;
    int half = lane >> 5;
    int block_row = blockIdx.x * 128;

    f32x16 acc[4];
    #pragma unroll
    for (int t = 0; t < 4; ++t)
        #pragma unroll
        for (int i = 0; i < 16; ++i) acc[t][i] = 0.0f;

    for (int kc = 0; kc < 4; ++kc) {
        const ushort* A = (kc < 2) ? xb : nbb;
        int k0 = (kc & 1) * 64;
        #pragma unroll
        for (int l = 0; l < 4; ++l) {
            int idx = l * 256 + tid;
            int r = idx >> 3;
            int p = idx & 7;
            int node = block_row + r;
            ushort8_t v;
            if (node < n) {
                v = *(const ushort8_t*)(A + (size_t)node * N_FEAT + k0 + p * 8);
            } else {
                #pragma unroll
                for (int q = 0; q < 8; ++q) v[q] = 0;
            }
            *(ushort8_t*)(&As[r * 72 + p * 8]) = v;
        }
        #pragma unroll
        for (int l = 0; l < 4; ++l) {
            int idx = l * 256 + tid;
            int cc = idx >> 3;
            int p = idx & 7;
            ushort8_t v = *(const ushort8_t*)(wt + (size_t)cc * 256 + kc * 64 + p * 8);
            *(ushort8_t*)(&Bs[cc * 72 + p * 8]) = v;
        }
        __syncthreads();
        #pragma unroll
        for (int ks = 0; ks < 4; ++ks) {
            int koff = ks * 16 + half * 8;
            short8 a = *(const short8*)(&As[(32 * wave + m) * 72 + koff]);
            short8 bf0 = *(const short8*)(&Bs[(0 * 32 + m) * 72 + koff]);
            short8 bf1 = *(const short8*)(&Bs[(1 * 32 + m) * 72 + koff]);
            short8 bf2 = *(const short8*)(&Bs[(2 * 32 + m) * 72 + koff]);
            short8 bf3 = *(const short8*)(&Bs[(3 * 32 + m) * 72 + koff]);
            acc[0] = __builtin_amdgcn_mfma_f32_32x32x16_bf16(a, bf0, acc[0], 0, 0, 0);
            acc[1] = __builtin_amdgcn_mfma_f32_32x32x16_bf16(a, bf1, acc[1], 0, 0, 0);
            acc[2] = __builtin_amdgcn_mfma_f32_32x32x16_bf16(a, bf2, acc[2], 0, 0, 0);
            acc[3] = __builtin_amdgcn_mfma_f32_32x32x16_bf16(a, bf3, acc[3], 0, 0, 0);
        }
        __syncthreads();
    }

    // epilogue: per lane, cols {m, 32+m, 64+m, 96+m}; rows (reg,half).
    float bcol[4], wsc[4][2], wnc[4][2];
    #pragma unroll
    for (int t = 0; t < 4; ++t) {
        int col = t * 32 + m;
        bcol[t] = b[col];
        float2 a = ((const float2*)ws2)[col];   // w_self2[col][0..1]
        float2 q = ((const float2*)wn2)[col];   // w_neigh2[col][0..1]
        wsc[t][0] = a.x; wsc[t][1] = a.y;
        wnc[t][0] = q.x; wnc[t][1] = q.y;
    }
    #pragma unroll
    for (int reg = 0; reg < 16; ++reg) {
        int rowin = (reg & 3) + 8 * (reg >> 2) + 4 * half;
        int node = block_row + 32 * wave + rowin;
        float p0 = 0.f, p1 = 0.f, q0 = 0.f, q1 = 0.f;
        #pragma unroll
        for (int t = 0; t < 4; ++t) {
            float hv = fmaxf(acc[t][reg] + bcol[t], 0.0f);
            p0 += hv * wsc[t][0]; p1 += hv * wsc[t][1];
            q0 += hv * wnc[t][0]; q1 += hv * wnc[t][1];
        }
        // reduce over the 32 lanes of this half (cols are disjoint across m)
        #pragma unroll
        for (int off = 1; off < 32; off <<= 1) {
            p0 += __shfl_xor(p0, off);
            p1 += __shfl_xor(p1, off);
            q0 += __shfl_xor(q0, off);
            q1 += __shfl_xor(q1, off);
        }
        if (m == 0 && node < n) {
            ((float2*)s_out)[node] = make_float2(p0, p1);
            ((float2*)z_out)[node] = make_float2(q0, q1);
        }
    }
}

// Layer-2 part B: 16 lanes per node; lane-per-edge z gather (L2-resident),
// shfl-xor group reduce, add self + bias, log_softmax.
__global__ __launch_bounds__(256) void layer2b_kernel(
    const float* __restrict__ s_in, const float* __restrict__ z,
    const int* __restrict__ row_ptr, const int* __restrict__ csr,
    const float* __restrict__ b, float* __restrict__ out, int n) {
    int v = blockIdx.x * 16 + (threadIdx.x >> 4);
    int sl = threadIdx.x & 15;
    if (v >= n) return;
    int beg = row_ptr[v];
    int end = row_ptr[v + 1];
    float a0 = 0.f, a1 = 0.f;
    for (int e = beg + sl; e < end; e += 16) {
        float2 t = ((const float2*)z)[csr[e]];
        a0 += t.x; a1 += t.y;
    }
    // reduce within the 16-lane group (xor offsets stay inside the group)
    #pragma unroll
    for (int off = 8; off > 0; off >>= 1) {
        a0 += __shfl_xor(a0, off);
        a1 += __shfl_xor(a1, off);
    }
    if (sl == 0) {
        int deg = end - beg;
        float inv = (deg > 0) ? 1.0f / (float)deg : 0.0f;
        float2 sv = ((const float2*)s_in)[v];
        float o0 = sv.x + a0 * inv + b[0];
        float o1 = sv.y + a1 * inv + b[1];
        float mx = fmaxf(o0, o1);
        float lse = mx + logf(expf(o0 - mx) + expf(o1 - mx));
        ((float2*)out)[v] = make_float2(o0 - lse, o1 - lse);
    }
}

extern "C" void kernel_launch(void* const* d_in, const int* in_sizes, int n_in,
                              void* d_out, int out_size, void* d_ws, size_t ws_size,
                              hipStream_t stream) {
    const float* x        = (const float*)d_in[0];
    const int*   src      = (const int*)d_in[1];
    const int*   dst      = (const int*)d_in[2];
    const float* w_self1  = (const float*)d_in[3];
    const float* w_neigh1 = (const float*)d_in[4];
    const float* b1       = (const float*)d_in[5];
    const float* w_self2  = (const float*)d_in[6];
    const float* w_neigh2 = (const float*)d_in[7];
    const float* b2       = (const float*)d_in[8];
    float* out = (float*)d_out;

    int N = in_sizes[0] / N_FEAT;
    int E = in_sizes[1];
    int nbk = (N + CNODES - 1) / CNODES;  // 196 for N=100000
    int nms = (E + BATCH - 1) / BATCH;    // 391 for E=1.6M

    char* ws = (char*)d_ws;
    size_t off = 0;
    auto alloc = [&](size_t bytes) -> void* {
        void* p = ws + off;
        off += (bytes + 255) & ~(size_t)255;
        return p;
    };
    int*      ccursor = (int*)alloc(NBINS * 4);
    int*      row_ptr = (int*)alloc((size_t)(N + 1) * 4);
    int*      csr     = (int*)alloc((size_t)E * 4);
    unsigned* cbuf    = (unsigned*)alloc((size_t)nbk * CCAP * 4);
    ushort*   xb      = (ushort*)alloc((size_t)N * N_FEAT * 2);
    ushort*   nbb     = (ushort*)alloc((size_t)N * N_FEAT * 2);
    ushort*   wt      = (ushort*)alloc((size_t)128 * 256 * 2);
    float*    s_buf   = (float*)alloc((size_t)N * 2 * 4);
    float*    z_buf   = (float*)alloc((size_t)N * 2 * 4);
    (void)ws_size; (void)n_in; (void)out_size;

    hipMemsetAsync(ccursor, 0, NBINS * 4, stream);

    prep_and_split_kernel<<<nms + BF_BLOCKS + PW_BLOCKS, 256, 0, stream>>>(
        src, dst, ccursor, cbuf, E, x, xb, N * N_FEAT / 4, w_self1, w_neigh1, wt, nms);
    build_csr2_kernel<<<nbk, 512, 0, stream>>>(cbuf, ccursor, row_ptr, csr, N, E);
    aggregate_bf16_kernel<<<(N + 3) / 4, 256, 0, stream>>>(xb, row_ptr, csr, nbb, N);
    gemm1_fused_kernel<<<(N + 127) / 128, 256, 0, stream>>>(
        xb, nbb, wt, b1, w_self2, w_neigh2, s_buf, z_buf, N);
    layer2b_kernel<<<(N + 15) / 16, 256, 0, stream>>>(s_buf, z_buf, row_ptr, csr, b2, out, N);
}